// Round 3
// baseline (21336.823 us; speedup 1.0000x reference)
//
#include <hip/hip_runtime.h>

// LSTM on MI355X — persistent kernel, round 2.
// Fixes vs R1: two-level grid barrier (8 padded sub-counters -> master -> 8
// epoch-flag copies), RELAXED polling + single acquire fence (no per-poll L2
// invalidate), per-thread release fences before arrival, x-part MFMAs of step
// t+1 overlapped with barrier propagation, 4 accumulator chains, fast gates.

namespace {
constexpr int T_STEPS = 512;
constexpr int BATCH   = 64;
constexpr int DI      = 512;
constexpr int DL      = 1024;
constexpr int NKC     = 48;   // K=1536 in chunks of 32
constexpr int NKC_H   = 32;   // h-part chunks (K=1024)
constexpr int NBLK    = 256;  // grid size == CU count (1 block/CU resident)
}

typedef __attribute__((ext_vector_type(8))) short bf16x8;
typedef __attribute__((ext_vector_type(8))) unsigned short u16x8;
typedef __attribute__((ext_vector_type(4))) float f32x4;

__device__ __forceinline__ unsigned short f2bf(float x){
  unsigned int u = __float_as_uint(x);
  return (unsigned short)((u + 0x7FFFu + ((u >> 16) & 1u)) >> 16);
}
__device__ __forceinline__ float bf2f(unsigned short b){
  return __uint_as_float(((unsigned int)b) << 16);
}
__device__ __forceinline__ float fast_sigmoid(float v){
  // 1/(1+e^-v); e^-v -> inf for very negative v gives 1/inf = 0 (correct)
  return __fdividef(1.f, 1.f + __expf(-v));
}
__device__ __forceinline__ float fast_tanh(float v){
  v = fminf(fmaxf(v, -15.f), 15.f);          // avoid inf/inf
  float t = __expf(2.f * v);
  return __fdividef(t - 1.f, t + 1.f);
}

// ---------------- prep: embeddings -> bf16 [T*B][DI] ----------------
__global__ void prep_xe(const int* __restrict__ X, const float* __restrict__ emb,
                        unsigned short* __restrict__ xe){
  int i = blockIdx.x * blockDim.x + threadIdx.x;      // one thread per 8 elems
  const int total = T_STEPS * BATCH * DI / 8;
  if (i >= total) return;
  int row = i >> 6;            // DI/8 = 64 segments per row; row = t*64+b
  int seg = i & 63;
  int tok = X[row];
  const float* src = emb + (long long)tok * DI + seg * 8;
  float4 v0 = *(const float4*)src;
  float4 v1 = *(const float4*)(src + 4);
  u16x8 o;
  o[0]=f2bf(v0.x); o[1]=f2bf(v0.y); o[2]=f2bf(v0.z); o[3]=f2bf(v0.w);
  o[4]=f2bf(v1.x); o[5]=f2bf(v1.y); o[6]=f2bf(v1.z); o[7]=f2bf(v1.w);
  *(u16x8*)(xe + (long long)row * DI + seg * 8) = o;
}

// ---------------- prep: pack W into MFMA B-fragment layout, hi/lo ----------------
__global__ void prep_w(const float* __restrict__ Wf, const float* __restrict__ Wi,
                       const float* __restrict__ Wc, const float* __restrict__ Wo,
                       unsigned short* __restrict__ W_hi, unsigned short* __restrict__ W_lo){
  int idx = blockIdx.x * blockDim.x + threadIdx.x;
  if (idx >= 256 * NKC * 64) return;
  int lane = idx & 63;
  int kc   = (idx >> 6) % NKC;
  int bk   = idx / (64 * NKC);
  int lc = lane & 15, kg = lane >> 4;
  int g  = lc >> 2;
  int jl = bk * 4 + (lc & 3);
  const float* Wg = (g == 0) ? Wf : ((g == 1) ? Wi : ((g == 2) ? Wc : Wo));
  int kbase = kc * 32 + kg * 8;
  u16x8 hi, lo;
#pragma unroll
  for (int j = 0; j < 8; j++){
    float wv = Wg[(long long)(kbase + j) * DL + jl];
    unsigned short h = f2bf(wv);
    hi[j] = h;
    lo[j] = f2bf(wv - bf2f(h));
  }
  *(u16x8*)(W_hi + ((long long)(bk * NKC + kc) * 64 + lane) * 8) = hi;
  if (kc < NKC_H)
    *(u16x8*)(W_lo + ((long long)(bk * NKC_H + kc) * 64 + lane) * 8) = lo;
}

// ---------------- prep: h0 -> hi/lo planes, bias pack, barrier zero ----------------
__global__ void prep_h(const float* __restrict__ h0,
                       const float* __restrict__ bf_, const float* __restrict__ bi_,
                       const float* __restrict__ bc_, const float* __restrict__ bo_,
                       unsigned short* __restrict__ h_hi, unsigned short* __restrict__ h_lo,
                       float* __restrict__ bias_pack, unsigned int* __restrict__ bar){
  int i = blockIdx.x * blockDim.x + threadIdx.x;
  if (i < BATCH * DL){
    float v = h0[i];
    unsigned short hb = f2bf(v);
    h_hi[i] = hb;
    h_lo[i] = f2bf(v - bf2f(hb));
  }
  if (i < 4096){
    int r = i & 3, g = (i >> 2) & 3, bk = i >> 4;
    const float* bg = (g == 0) ? bf_ : ((g == 1) ? bi_ : ((g == 2) ? bc_ : bo_));
    bias_pack[i] = bg[bk * 4 + r];
  }
  if (i < 2048) bar[i] = 0u;
}

// barrier layout (uint indices into bar): sub-counter x -> x*64 (x=0..7),
// master -> 512, epoch copy e -> 576 + e*64 (e=0..7). 256B padding between.

// ---------------- persistent LSTM: all 512 steps in one kernel ----------------
__launch_bounds__(256, 1)
__global__ void lstm_persist(const unsigned short* __restrict__ xe,
                             const unsigned short* __restrict__ W_hi,
                             const unsigned short* __restrict__ W_lo,
                             unsigned short* __restrict__ h_hi,   // [2][B*DL]
                             unsigned short* __restrict__ h_lo,   // [2][B*DL]
                             const float* __restrict__ bias_pack,
                             float* __restrict__ out,
                             unsigned int* __restrict__ bar){
  extern __shared__ unsigned short lds[];
  unsigned short* lds_hi = lds;              // NKC  *512 elems (48 KB)
  unsigned short* lds_lo = lds + NKC * 512;  // NKC_H*512 elems (32 KB)
  const int tid  = threadIdx.x;
  const int bk   = blockIdx.x;
  const int w    = tid >> 6;
  const int lane = tid & 63;

  // stage W once for the whole run
  const uint4* srcHi = (const uint4*)(W_hi + (size_t)bk * NKC * 512);
  uint4* dHi = (uint4*)lds_hi;
  for (int i = tid; i < 3072; i += 256) dHi[i] = srcHi[i];
  const uint4* srcLo = (const uint4*)(W_lo + (size_t)bk * NKC_H * 512);
  uint4* dLo = (uint4*)lds_lo;
  for (int i = tid; i < 2048; i += 256) dLo[i] = srcLo[i];
  __syncthreads();

  const int lc = lane & 15;
  const int kg = lane >> 4;
  const int g  = lc >> 2;
  const int rowb = (w << 4) + lc;            // A-frag batch row
  const float bias = bias_pack[bk * 16 + lc];
  const int srcBase = (lane & 48) | (lc & 3);
  const int hOff = rowb * DL + kg * 8;
  const int xOff = rowb * DI + kg * 8;
  unsigned int* subCtr = bar + (bk & 7) * 64;
  unsigned int* master = bar + 512;
  unsigned int* myEpoch = bar + 576 + (bk & 7) * 64;
  float cr0 = 0.f, cr1 = 0.f, cr2 = 0.f, cr3 = 0.f;   // c-state (g==0 lanes)

  f32x4 acc0 = {0.f,0.f,0.f,0.f}, acc1 = {0.f,0.f,0.f,0.f};
  f32x4 acc2 = {0.f,0.f,0.f,0.f}, acc3 = {0.f,0.f,0.f,0.f};

#define XSTEP(KC, ACC) {                                                        \
    bf16x8 ax = *(const bf16x8*)(xRow + (KC) * 32);                             \
    bf16x8 bh = *(const bf16x8*)(lds_hi + (NKC_H + (KC)) * 512 + lane * 8);     \
    ACC = __builtin_amdgcn_mfma_f32_16x16x32_bf16(ax, bh, ACC, 0, 0, 0); }
#define HSTEP(KC, ACC) {                                                        \
    bf16x8 ah = *(const bf16x8*)(hRowHi + (KC) * 32);                           \
    bf16x8 al = *(const bf16x8*)(hRowLo + (KC) * 32);                           \
    bf16x8 bh = *(const bf16x8*)(lds_hi + (KC) * 512 + lane * 8);               \
    bf16x8 bl = *(const bf16x8*)(lds_lo + (KC) * 512 + lane * 8);               \
    ACC = __builtin_amdgcn_mfma_f32_16x16x32_bf16(ah, bh, ACC, 0, 0, 0);        \
    ACC = __builtin_amdgcn_mfma_f32_16x16x32_bf16(ah, bl, ACC, 0, 0, 0);        \
    ACC = __builtin_amdgcn_mfma_f32_16x16x32_bf16(al, bh, ACC, 0, 0, 0); }

  // x-part for step 0
  {
    const unsigned short* xRow = xe + xOff;
#pragma unroll
    for (int kc = 0; kc < 16; kc += 4){
      XSTEP(kc, acc0) XSTEP(kc + 1, acc1) XSTEP(kc + 2, acc2) XSTEP(kc + 3, acc3)
    }
  }

#pragma unroll 1
  for (int t = 0; t < T_STEPS; ++t){
    // ---- wait for h_t (epoch >= t), then acquire ----
    if (tid == 0){
      const unsigned tgt = (unsigned)t;
      int spin = 0;
      while (__hip_atomic_load(myEpoch, __ATOMIC_RELAXED, __HIP_MEMORY_SCOPE_AGENT) < tgt){
        __builtin_amdgcn_s_sleep(2);
        if (++spin > (1 << 16)) break;     // bail out loud (absmax), don't hang
      }
    }
    __syncthreads();
    __builtin_amdgcn_fence(__ATOMIC_ACQUIRE, "agent");

    const int rb = t & 1;
    const unsigned short* hRowHi = h_hi + rb * (BATCH * DL) + hOff;
    const unsigned short* hRowLo = h_lo + rb * (BATCH * DL) + hOff;
    unsigned short* hWHi = h_hi + (rb ^ 1) * (BATCH * DL);
    unsigned short* hWLo = h_lo + (rb ^ 1) * (BATCH * DL);
    float* out_t = out + (size_t)t * BATCH * DL;

    // ---- h-part: 3-term split-bf16 over K=1024, 4 chains ----
#pragma unroll
    for (int kc = 0; kc < NKC_H; kc += 4){
      HSTEP(kc, acc0) HSTEP(kc + 1, acc1) HSTEP(kc + 2, acc2) HSTEP(kc + 3, acc3)
    }
    f32x4 acc = (acc0 + acc1) + (acc2 + acc3);

    // ---- epilogue: gather f/i/c/o via shfl, gate math, write h_{t+1}/out ----
    float creg[4] = {cr0, cr1, cr2, cr3};
#pragma unroll
    for (int r = 0; r < 4; r++){
      float v = acc[r] + bias;
      float vF = __shfl(v, srcBase);
      float vI = __shfl(v, srcBase + 4);
      float vC = __shfl(v, srcBase + 8);
      float vO = __shfl(v, srcBase + 12);
      if (g == 0){
        int b = (w << 4) | (kg << 2) | r;
        int j = (bk << 2) | (lc & 3);
        float ft = fast_sigmoid(vF);
        float it = fast_sigmoid(vI);
        float gt = fast_tanh(vC);
        float ot = fast_sigmoid(vO);
        float cn = ft * creg[r] + it * gt;
        creg[r] = cn;
        float hn = ot * fast_tanh(cn);
        int ci = b * DL + j;
        out_t[ci] = hn;
        unsigned short hb = f2bf(hn);
        hWHi[ci] = hb;
        hWLo[ci] = f2bf(hn - bf2f(hb));
      }
    }
    cr0 = creg[0]; cr1 = creg[1]; cr2 = creg[2]; cr3 = creg[3];

    // ---- release my writes (every thread drains its own stores), arrive ----
    __builtin_amdgcn_fence(__ATOMIC_RELEASE, "agent");
    __syncthreads();
    if (tid == 0){
      unsigned so = __hip_atomic_fetch_add(subCtr, 1u, __ATOMIC_ACQ_REL, __HIP_MEMORY_SCOPE_AGENT);
      if (so == 32u * (unsigned)(t + 1) - 1u){
        unsigned mo = __hip_atomic_fetch_add(master, 1u, __ATOMIC_ACQ_REL, __HIP_MEMORY_SCOPE_AGENT);
        if (mo == 8u * (unsigned)(t + 1) - 1u){
#pragma unroll
          for (int e = 0; e < 8; e++)
            __hip_atomic_store(bar + 576 + e * 64, (unsigned)(t + 1),
                               __ATOMIC_RELEASE, __HIP_MEMORY_SCOPE_AGENT);
        }
      }
    }

    // ---- overlap: x-part MFMAs for step t+1 (xe independent of h) ----
    acc0 = (f32x4){0.f,0.f,0.f,0.f}; acc1 = (f32x4){0.f,0.f,0.f,0.f};
    acc2 = (f32x4){0.f,0.f,0.f,0.f}; acc3 = (f32x4){0.f,0.f,0.f,0.f};
    if (t + 1 < T_STEPS){
      const unsigned short* xRow = xe + (size_t)(t + 1) * BATCH * DI + xOff;
#pragma unroll
      for (int kc = 0; kc < 16; kc += 4){
        XSTEP(kc, acc0) XSTEP(kc + 1, acc1) XSTEP(kc + 2, acc2) XSTEP(kc + 3, acc3)
      }
    }
  }
#undef XSTEP
#undef HSTEP
}

extern "C" void kernel_launch(void* const* d_in, const int* in_sizes, int n_in,
                              void* d_out, int out_size, void* d_ws, size_t ws_size,
                              hipStream_t stream){
  const int*   X   = (const int*)d_in[0];
  const float* h0  = (const float*)d_in[1];
  const float* emb = (const float*)d_in[2];
  const float* Wf  = (const float*)d_in[3];
  const float* bf_ = (const float*)d_in[4];
  const float* Wi  = (const float*)d_in[5];
  const float* bi_ = (const float*)d_in[6];
  const float* Wc  = (const float*)d_in[7];
  const float* bc_ = (const float*)d_in[8];
  const float* Wo  = (const float*)d_in[9];
  const float* bo_ = (const float*)d_in[10];
  float* out = (float*)d_out;

  char* ws = (char*)d_ws;
  size_t off = 0;
  auto alloc = [&](size_t bytes) -> void* {
    void* p = ws + off;
    off = (off + bytes + 255) & ~((size_t)255);
    return p;
  };
  unsigned short* xe        = (unsigned short*)alloc(sizeof(unsigned short) * (size_t)T_STEPS * BATCH * DI);
  unsigned short* W_hi      = (unsigned short*)alloc(sizeof(unsigned short) * (size_t)256 * NKC * 512);
  unsigned short* W_lo      = (unsigned short*)alloc(sizeof(unsigned short) * (size_t)256 * NKC_H * 512);
  unsigned short* h_hi      = (unsigned short*)alloc(sizeof(unsigned short) * 2 * BATCH * DL);
  unsigned short* h_lo      = (unsigned short*)alloc(sizeof(unsigned short) * 2 * BATCH * DL);
  float*          bias_pack = (float*)alloc(sizeof(float) * 4096);
  unsigned int*   bar       = (unsigned int*)alloc(sizeof(unsigned int) * 2048);
  (void)ws_size; (void)in_sizes; (void)n_in; (void)out_size;

  static bool attr_set = false;
  if (!attr_set){
    hipFuncSetAttribute((const void*)lstm_persist,
                        hipFuncAttributeMaxDynamicSharedMemorySize, 160 * 1024);
    attr_set = true;
  }

  hipLaunchKernelGGL(prep_xe, dim3(8192), dim3(256), 0, stream, X, emb, xe);
  hipLaunchKernelGGL(prep_w,  dim3(3072), dim3(256), 0, stream, Wf, Wi, Wc, Wo, W_hi, W_lo);
  hipLaunchKernelGGL(prep_h,  dim3(256),  dim3(256), 0, stream, h0, bf_, bi_, bc_, bo_,
                     h_hi, h_lo, bias_pack, bar);
  hipLaunchKernelGGL(lstm_persist, dim3(NBLK), dim3(256), 80 * 1024, stream,
                     xe, W_hi, W_lo, h_hi, h_lo, bias_pack, out, bar);
}

// Round 4
// 6443.046 us; speedup vs baseline: 3.3116x; 3.3116x over previous
//
#include <hip/hip_runtime.h>

// LSTM on MI355X — persistent kernel, round 3.
// Barrier rebuilt: per-block padded epoch flags (no RMW contention), h-state
// written WRITE-THROUGH (system-scope relaxed atomic stores -> no L2 writeback
// fence needed), distributed flag scan by wave 0 of every block, single
// agent-acquire fence per block per step (wave 0 only). Numerics identical.

namespace {
constexpr int T_STEPS = 512;
constexpr int BATCH   = 64;
constexpr int DI      = 512;
constexpr int DL      = 1024;
constexpr int NKC     = 48;   // K=1536 in chunks of 32
constexpr int NKC_H   = 32;   // h-part chunks (K=1024)
constexpr int NBLK    = 256;  // grid == CU count, 1 block/CU resident
constexpr int FPAD    = 32;   // uints per flag slot (128 B padding)
}

typedef __attribute__((ext_vector_type(8))) short bf16x8;
typedef __attribute__((ext_vector_type(8))) unsigned short u16x8;
typedef __attribute__((ext_vector_type(4))) float f32x4;

__device__ __forceinline__ unsigned short f2bf(float x){
  unsigned int u = __float_as_uint(x);
  return (unsigned short)((u + 0x7FFFu + ((u >> 16) & 1u)) >> 16);
}
__device__ __forceinline__ float bf2f(unsigned short b){
  return __uint_as_float(((unsigned int)b) << 16);
}
__device__ __forceinline__ float fast_sigmoid(float v){
  return __fdividef(1.f, 1.f + __expf(-v));
}
__device__ __forceinline__ float fast_tanh(float v){
  v = fminf(fmaxf(v, -15.f), 15.f);
  float t = __expf(2.f * v);
  return __fdividef(t - 1.f, t + 1.f);
}
__device__ __forceinline__ void st_wt_u16(unsigned short* p, unsigned short v){
  // write-through to coherence point: no dirty L2 line, cross-XCD visible
  // once vmcnt drains (no wbl2 fence needed before the epoch-flag store)
  __hip_atomic_store(p, v, __ATOMIC_RELAXED, __HIP_MEMORY_SCOPE_SYSTEM);
}

// ---------------- prep: embeddings -> bf16 [T*B][DI] ----------------
__global__ void prep_xe(const int* __restrict__ X, const float* __restrict__ emb,
                        unsigned short* __restrict__ xe){
  int i = blockIdx.x * blockDim.x + threadIdx.x;
  const int total = T_STEPS * BATCH * DI / 8;
  if (i >= total) return;
  int row = i >> 6;
  int seg = i & 63;
  int tok = X[row];
  const float* src = emb + (long long)tok * DI + seg * 8;
  float4 v0 = *(const float4*)src;
  float4 v1 = *(const float4*)(src + 4);
  u16x8 o;
  o[0]=f2bf(v0.x); o[1]=f2bf(v0.y); o[2]=f2bf(v0.z); o[3]=f2bf(v0.w);
  o[4]=f2bf(v1.x); o[5]=f2bf(v1.y); o[6]=f2bf(v1.z); o[7]=f2bf(v1.w);
  *(u16x8*)(xe + (long long)row * DI + seg * 8) = o;
}

// ---------------- prep: pack W into MFMA B-fragment layout, hi/lo ----------------
__global__ void prep_w(const float* __restrict__ Wf, const float* __restrict__ Wi,
                       const float* __restrict__ Wc, const float* __restrict__ Wo,
                       unsigned short* __restrict__ W_hi, unsigned short* __restrict__ W_lo){
  int idx = blockIdx.x * blockDim.x + threadIdx.x;
  if (idx >= 256 * NKC * 64) return;
  int lane = idx & 63;
  int kc   = (idx >> 6) % NKC;
  int bk   = idx / (64 * NKC);
  int lc = lane & 15, kg = lane >> 4;
  int g  = lc >> 2;
  int jl = bk * 4 + (lc & 3);
  const float* Wg = (g == 0) ? Wf : ((g == 1) ? Wi : ((g == 2) ? Wc : Wo));
  int kbase = kc * 32 + kg * 8;
  u16x8 hi, lo;
#pragma unroll
  for (int j = 0; j < 8; j++){
    float wv = Wg[(long long)(kbase + j) * DL + jl];
    unsigned short h = f2bf(wv);
    hi[j] = h;
    lo[j] = f2bf(wv - bf2f(h));
  }
  *(u16x8*)(W_hi + ((long long)(bk * NKC + kc) * 64 + lane) * 8) = hi;
  if (kc < NKC_H)
    *(u16x8*)(W_lo + ((long long)(bk * NKC_H + kc) * 64 + lane) * 8) = lo;
}

// ---------------- prep: h0 -> hi/lo planes, bias pack, flags zero ----------------
__global__ void prep_h(const float* __restrict__ h0,
                       const float* __restrict__ bf_, const float* __restrict__ bi_,
                       const float* __restrict__ bc_, const float* __restrict__ bo_,
                       unsigned short* __restrict__ h_hi, unsigned short* __restrict__ h_lo,
                       float* __restrict__ bias_pack, unsigned int* __restrict__ bar){
  int i = blockIdx.x * blockDim.x + threadIdx.x;
  if (i < BATCH * DL){
    float v = h0[i];
    unsigned short hb = f2bf(v);
    h_hi[i] = hb;
    h_lo[i] = f2bf(v - bf2f(hb));
  }
  if (i < 4096){
    int r = i & 3, g = (i >> 2) & 3, bk = i >> 4;
    const float* bg = (g == 0) ? bf_ : ((g == 1) ? bi_ : ((g == 2) ? bc_ : bo_));
    bias_pack[i] = bg[bk * 4 + r];
  }
  if (i < NBLK * FPAD) bar[i] = 0u;
}

// ---------------- persistent LSTM: all 512 steps in one kernel ----------------
__launch_bounds__(256, 1)
__global__ void lstm_persist(const unsigned short* __restrict__ xe,
                             const unsigned short* __restrict__ W_hi,
                             const unsigned short* __restrict__ W_lo,
                             unsigned short* __restrict__ h_hi,   // [2][B*DL]
                             unsigned short* __restrict__ h_lo,   // [2][B*DL]
                             const float* __restrict__ bias_pack,
                             float* __restrict__ out,
                             unsigned int* __restrict__ bar){
  extern __shared__ unsigned short lds[];
  unsigned short* lds_hi = lds;              // NKC  *512 elems (48 KB)
  unsigned short* lds_lo = lds + NKC * 512;  // NKC_H*512 elems (32 KB)
  const int tid  = threadIdx.x;
  const int bk   = blockIdx.x;
  const int w    = tid >> 6;
  const int lane = tid & 63;

  // stage W once for the whole run
  const uint4* srcHi = (const uint4*)(W_hi + (size_t)bk * NKC * 512);
  uint4* dHi = (uint4*)lds_hi;
  for (int i = tid; i < 3072; i += 256) dHi[i] = srcHi[i];
  const uint4* srcLo = (const uint4*)(W_lo + (size_t)bk * NKC_H * 512);
  uint4* dLo = (uint4*)lds_lo;
  for (int i = tid; i < 2048; i += 256) dLo[i] = srcLo[i];
  __syncthreads();

  const int lc = lane & 15;
  const int kg = lane >> 4;
  const int g  = lc >> 2;
  const int rowb = (w << 4) + lc;
  const float bias = bias_pack[bk * 16 + lc];
  const int srcBase = (lane & 48) | (lc & 3);
  const int hOff = rowb * DL + kg * 8;
  const int xOff = rowb * DI + kg * 8;
  float cr0 = 0.f, cr1 = 0.f, cr2 = 0.f, cr3 = 0.f;

  f32x4 acc0 = {0.f,0.f,0.f,0.f}, acc1 = {0.f,0.f,0.f,0.f};
  f32x4 acc2 = {0.f,0.f,0.f,0.f}, acc3 = {0.f,0.f,0.f,0.f};

#define XSTEP(KC, ACC) {                                                        \
    bf16x8 ax = *(const bf16x8*)(xRow + (KC) * 32);                             \
    bf16x8 bh = *(const bf16x8*)(lds_hi + (NKC_H + (KC)) * 512 + lane * 8);     \
    ACC = __builtin_amdgcn_mfma_f32_16x16x32_bf16(ax, bh, ACC, 0, 0, 0); }
#define HSTEP(KC, ACC) {                                                        \
    bf16x8 ah = *(const bf16x8*)(hRowHi + (KC) * 32);                           \
    bf16x8 al = *(const bf16x8*)(hRowLo + (KC) * 32);                           \
    bf16x8 bh = *(const bf16x8*)(lds_hi + (KC) * 512 + lane * 8);               \
    bf16x8 bl = *(const bf16x8*)(lds_lo + (KC) * 512 + lane * 8);               \
    ACC = __builtin_amdgcn_mfma_f32_16x16x32_bf16(ah, bh, ACC, 0, 0, 0);        \
    ACC = __builtin_amdgcn_mfma_f32_16x16x32_bf16(ah, bl, ACC, 0, 0, 0);        \
    ACC = __builtin_amdgcn_mfma_f32_16x16x32_bf16(al, bh, ACC, 0, 0, 0); }

  // x-part for step 0
  {
    const unsigned short* xRow = xe + xOff;
#pragma unroll
    for (int kc = 0; kc < 16; kc += 4){
      XSTEP(kc, acc0) XSTEP(kc + 1, acc1) XSTEP(kc + 2, acc2) XSTEP(kc + 3, acc3)
    }
  }

#pragma unroll 1
  for (int t = 0; t < T_STEPS; ++t){
    // ---- wait: all 256 epoch flags >= t (h_t published), then acquire ----
    if (w == 0 && t > 0){
      const unsigned tgt = (unsigned)t;
      int spin = 0;
      for (;;){
        unsigned v0 = __hip_atomic_load(bar + (lane       ) * FPAD, __ATOMIC_RELAXED, __HIP_MEMORY_SCOPE_AGENT);
        unsigned v1 = __hip_atomic_load(bar + (lane +  64 ) * FPAD, __ATOMIC_RELAXED, __HIP_MEMORY_SCOPE_AGENT);
        unsigned v2 = __hip_atomic_load(bar + (lane + 128 ) * FPAD, __ATOMIC_RELAXED, __HIP_MEMORY_SCOPE_AGENT);
        unsigned v3 = __hip_atomic_load(bar + (lane + 192 ) * FPAD, __ATOMIC_RELAXED, __HIP_MEMORY_SCOPE_AGENT);
        bool ok = (v0 >= tgt) & (v1 >= tgt) & (v2 >= tgt) & (v3 >= tgt);
        if (__all(ok ? 1 : 0)) break;
        __builtin_amdgcn_s_sleep(8);
        if (++spin > (1 << 14)) break;   // bail loud (absmax), don't hang
      }
      // invalidate stale L1/L2 copies of the reused h double-buffer
      __builtin_amdgcn_fence(__ATOMIC_ACQUIRE, "agent");
    }
    __syncthreads();

    const int rb = t & 1;
    const unsigned short* hRowHi = h_hi + rb * (BATCH * DL) + hOff;
    const unsigned short* hRowLo = h_lo + rb * (BATCH * DL) + hOff;
    unsigned short* hWHi = h_hi + (rb ^ 1) * (BATCH * DL);
    unsigned short* hWLo = h_lo + (rb ^ 1) * (BATCH * DL);
    float* out_t = out + (size_t)t * BATCH * DL;

    // ---- h-part: 3-term split-bf16 over K=1024, 4 chains ----
#pragma unroll
    for (int kc = 0; kc < NKC_H; kc += 4){
      HSTEP(kc, acc0) HSTEP(kc + 1, acc1) HSTEP(kc + 2, acc2) HSTEP(kc + 3, acc3)
    }
    f32x4 acc = (acc0 + acc1) + (acc2 + acc3);

    // ---- epilogue: gather f/i/c/o via shfl, gates, write h_{t+1}/out ----
    float creg[4] = {cr0, cr1, cr2, cr3};
#pragma unroll
    for (int r = 0; r < 4; r++){
      float v = acc[r] + bias;
      float vF = __shfl(v, srcBase);
      float vI = __shfl(v, srcBase + 4);
      float vC = __shfl(v, srcBase + 8);
      float vO = __shfl(v, srcBase + 12);
      if (g == 0){
        int b = (w << 4) | (kg << 2) | r;
        int j = (bk << 2) | (lc & 3);
        float ft = fast_sigmoid(vF);
        float it = fast_sigmoid(vI);
        float gt = fast_tanh(vC);
        float ot = fast_sigmoid(vO);
        float cn = ft * creg[r] + it * gt;
        creg[r] = cn;
        float hn = ot * fast_tanh(cn);
        int ci = b * DL + j;
        out_t[ci] = hn;                          // plain store (host-read only)
        unsigned short hb = f2bf(hn);
        st_wt_u16(&hWHi[ci], hb);                // write-through: visible at
        st_wt_u16(&hWLo[ci], f2bf(hn - bf2f(hb))); // coherence point on vmcnt drain
      }
    }
    cr0 = creg[0]; cr1 = creg[1]; cr2 = creg[2]; cr3 = creg[3];

    // ---- arrive: all waves' stores drained by barrier, then publish epoch ----
    __syncthreads();
    if (tid == 0)
      __hip_atomic_store(bar + bk * FPAD, (unsigned)(t + 1),
                         __ATOMIC_RELAXED, __HIP_MEMORY_SCOPE_AGENT);

    // ---- overlap: x-part MFMAs for step t+1 (xe independent of h) ----
    acc0 = (f32x4){0.f,0.f,0.f,0.f}; acc1 = (f32x4){0.f,0.f,0.f,0.f};
    acc2 = (f32x4){0.f,0.f,0.f,0.f}; acc3 = (f32x4){0.f,0.f,0.f,0.f};
    if (t + 1 < T_STEPS){
      const unsigned short* xRow = xe + (size_t)(t + 1) * BATCH * DI + xOff;
#pragma unroll
      for (int kc = 0; kc < 16; kc += 4){
        XSTEP(kc, acc0) XSTEP(kc + 1, acc1) XSTEP(kc + 2, acc2) XSTEP(kc + 3, acc3)
      }
    }
  }
#undef XSTEP
#undef HSTEP
}

extern "C" void kernel_launch(void* const* d_in, const int* in_sizes, int n_in,
                              void* d_out, int out_size, void* d_ws, size_t ws_size,
                              hipStream_t stream){
  const int*   X   = (const int*)d_in[0];
  const float* h0  = (const float*)d_in[1];
  const float* emb = (const float*)d_in[2];
  const float* Wf  = (const float*)d_in[3];
  const float* bf_ = (const float*)d_in[4];
  const float* Wi  = (const float*)d_in[5];
  const float* bi_ = (const float*)d_in[6];
  const float* Wc  = (const float*)d_in[7];
  const float* bc_ = (const float*)d_in[8];
  const float* Wo  = (const float*)d_in[9];
  const float* bo_ = (const float*)d_in[10];
  float* out = (float*)d_out;

  char* ws = (char*)d_ws;
  size_t off = 0;
  auto alloc = [&](size_t bytes) -> void* {
    void* p = ws + off;
    off = (off + bytes + 255) & ~((size_t)255);
    return p;
  };
  unsigned short* xe        = (unsigned short*)alloc(sizeof(unsigned short) * (size_t)T_STEPS * BATCH * DI);
  unsigned short* W_hi      = (unsigned short*)alloc(sizeof(unsigned short) * (size_t)256 * NKC * 512);
  unsigned short* W_lo      = (unsigned short*)alloc(sizeof(unsigned short) * (size_t)256 * NKC_H * 512);
  unsigned short* h_hi      = (unsigned short*)alloc(sizeof(unsigned short) * 2 * BATCH * DL);
  unsigned short* h_lo      = (unsigned short*)alloc(sizeof(unsigned short) * 2 * BATCH * DL);
  float*          bias_pack = (float*)alloc(sizeof(float) * 4096);
  unsigned int*   bar       = (unsigned int*)alloc(sizeof(unsigned int) * NBLK * FPAD);
  (void)ws_size; (void)in_sizes; (void)n_in; (void)out_size;

  static bool attr_set = false;
  if (!attr_set){
    hipFuncSetAttribute((const void*)lstm_persist,
                        hipFuncAttributeMaxDynamicSharedMemorySize, 160 * 1024);
    attr_set = true;
  }

  hipLaunchKernelGGL(prep_xe, dim3(8192), dim3(256), 0, stream, X, emb, xe);
  hipLaunchKernelGGL(prep_w,  dim3(3072), dim3(256), 0, stream, Wf, Wi, Wc, Wo, W_hi, W_lo);
  hipLaunchKernelGGL(prep_h,  dim3(256),  dim3(256), 0, stream, h0, bf_, bi_, bc_, bo_,
                     h_hi, h_lo, bias_pack, bar);
  hipLaunchKernelGGL(lstm_persist, dim3(NBLK), dim3(256), 80 * 1024, stream,
                     xe, W_hi, W_lo, h_hi, h_lo, bias_pack, out, bar);
}